// Round 13
// baseline (496.497 us; speedup 1.0000x reference)
//
#include <hip/hip_runtime.h>
#include <math.h>

// ---------------- types ----------------
typedef float  f32x4  __attribute__((ext_vector_type(4)));
typedef short  bf16x8 __attribute__((ext_vector_type(8)));

#define NTOK 8192
#define H    1024
#define FF   4096
#define NEXP 8
#define MAXT128 72   // 128-row tiles: sum ceil(c_e/128) <= 8192/128 + 8

// fp32 -> bf16 RNE
__device__ __forceinline__ unsigned short f2bf(float f) {
    unsigned int u = __float_as_uint(f);
    u += 0x7fffu + ((u >> 16) & 1u);
    return (unsigned short)(u >> 16);
}

__device__ __forceinline__ ushort4 cvt4(float4 v) {
    return make_ushort4(f2bf(v.x), f2bf(v.y), f2bf(v.z), f2bf(v.w));
}

// async global->LDS, 16B/lane; LDS dest = wave-uniform base + lane*16
__device__ __forceinline__ void gload16(const void* g, void* l) {
    __builtin_amdgcn_global_load_lds((const __attribute__((address_space(1))) void*)g,
                                     (__attribute__((address_space(3))) void*)l, 16, 0, 0);
}

// ---------------- router: 1 wave per token ----------------
__global__ void __launch_bounds__(256)
router_k(const float* __restrict__ x, const float* __restrict__ rw, const float* __restrict__ rb,
         float* __restrict__ maxp, int* __restrict__ maxi, int* __restrict__ counts) {
    const int lane = threadIdx.x & 63;
    const int t = blockIdx.x * 4 + (threadIdx.x >> 6);
    const float4* xr = (const float4*)(x + (size_t)t * H);
    float acc[NEXP];
#pragma unroll
    for (int e = 0; e < NEXP; ++e) acc[e] = 0.f;
#pragma unroll
    for (int c = 0; c < 4; ++c) {
        float4 xv = xr[lane + 64 * c];
#pragma unroll
        for (int e = 0; e < NEXP; ++e) {
            float4 wv = ((const float4*)(rw + e * H))[lane + 64 * c];
            acc[e] += xv.x * wv.x + xv.y * wv.y + xv.z * wv.z + xv.w * wv.w;
        }
    }
#pragma unroll
    for (int e = 0; e < NEXP; ++e) {
#pragma unroll
        for (int off = 32; off > 0; off >>= 1) acc[e] += __shfl_xor(acc[e], off);
    }
    if (lane == 0) {
        float best = -1e30f; int bi = 0;
#pragma unroll
        for (int e = 0; e < NEXP; ++e) {
            float v = acc[e] + rb[e];
            acc[e] = v;
            if (v > best) { best = v; bi = e; }   // first-max tie-break like jnp.argmax
        }
        float s = 0.f;
#pragma unroll
        for (int e = 0; e < NEXP; ++e) s += __expf(acc[e] - best);
        maxp[t] = 1.0f / s;                       // max of softmax
        maxi[t] = bi;
        atomicAdd(&counts[bi * 32], 1);           // 128B-padded: 8 independent L2 lines
    }
}

// ---------------- scan: bucket offsets (128-aligned) + 128-row tile table ----------------
__global__ void scan_k(const int* __restrict__ counts, int* __restrict__ offs,
                       int* __restrict__ tile_e, int* __restrict__ tile_r0, int* __restrict__ ntiles) {
    int off = 0, ti = 0;
    for (int e = 0; e < NEXP; ++e) {
        offs[e] = off;
        int nt = (counts[e * 32] + 127) >> 7;
        for (int j = 0; j < nt; ++j) { tile_e[ti] = e; tile_r0[ti] = off + (j << 7); ++ti; }
        off += nt << 7;
    }
    offs[NEXP] = off;
    *ntiles = ti;
}

// ---------------- gather tokens into bucketed bf16 A ----------------
__global__ void __launch_bounds__(256)
gather_k(const float* __restrict__ x, const int* __restrict__ maxi, const int* __restrict__ offs,
         int* __restrict__ cursor, int* __restrict__ perm, unsigned short* __restrict__ ab) {
    const int lane = threadIdx.x & 63;
    const int t = blockIdx.x * 4 + (threadIdx.x >> 6);
    int pos = 0;
    if (lane == 0) {
        int e = maxi[t];
        pos = offs[e] + atomicAdd(&cursor[e * 32], 1);   // padded cursors
        perm[pos] = t;
    }
    pos = __shfl(pos, 0);
    const float4* xr = (const float4*)(x + (size_t)t * H);
    ushort4* ar = (ushort4*)(ab + (size_t)pos * H);
#pragma unroll
    for (int c = 0; c < 4; ++c) {
        float4 v = xr[lane + 64 * c];
        ar[lane + 64 * c] = cvt4(v);
    }
}

// ---------------- GEMM core 128x128, fp32 B ----------------
// C[128x128] += A[128xK](bf16, stride KB bytes) * B[128xK](FP32, stride KBB bytes)^T.
// r1/r5 proven m97 structure unchanged (2 barriers / 64-elem K-step, 16x16x32 MFMA,
// identical swizzled LDS layout + read path). ONLY the B staging path differs:
// global fp32 -> regs -> v_cvt_pk_bf16_f32 -> ds_write_b128 at the same physical
// LDS bytes the DMA produced (phys = r*128 + (lcb ^ ((r&7)<<4))). This deletes the
// standalone 576MB cvt pass; LDS traffic is unchanged (same bf16 bytes written/read).
template<int KB, int KBB>   // KB: A row stride bytes (=2K); KBB: B fp32 row stride bytes (=4K)
__device__ __forceinline__ void gemm_core(const char* Ag, const char* Bg,
                                          unsigned short* As, unsigned short* Bs,
                                          f32x4 (&acc)[4][4]) {
    const int tid  = threadIdx.x;
    const int lane = tid & 63;
    const int wv   = tid >> 6;          // 4 waves, 2x2 over tile; each wave 64x64
    const int wr   = wv >> 1, wc = wv & 1;

    // A staging (global_load_lds DMA, verbatim from r1)
    int goff[4];
#pragma unroll
    for (int c = 0; c < 4; ++c) {
        int op = c * 4096 + wv * 1024 + lane * 16;          // physical LDS byte this lane fills
        int ol = op ^ (((op >> 7) & 7) << 4);               // logical offset (swz is an involution)
        goff[c] = (ol >> 7) * KB + (ol & 127);              // row*stride + col bytes
    }
    // B reg-staging geometry: thread covers B row br, col-half bch (32 fp32 = 128B in,
    // 64B bf16 out as 4x16B ds_writes at the swizzled physical offsets).
    const int br  = tid >> 1;
    const int bch = tid & 1;
    const char* bsrc = Bg + (size_t)br * KBB + bch * 128;
    char* bdst[4];
#pragma unroll
    for (int q = 0; q < 4; ++q) {
        const int lcb = bch * 64 + q * 16;
        bdst[q] = (char*)Bs + br * 128 + (lcb ^ ((br & 7) << 4));
    }

    const int rA  = (wr * 64 + (lane & 15)) * 128;
    const int rB  = (wc * 64 + (lane & 15)) * 128;
    const int xr  = (lane & 7) << 4;                        // (row&7)<<4 swizzle on read
    const int cb0 = (lane >> 4) << 4;

#pragma unroll 1
    for (int kt = 0; kt < KB / 128; ++kt) {
        const int kb = kt * 128;
#pragma unroll
        for (int c = 0; c < 4; ++c)
            gload16(Ag + goff[c] + kb, (char*)As + c * 4096 + wv * 1024);
        // B: load 8x float4 fp32 (this thread's 128B), convert, write 4x16B to LDS
        f32x4 t[8];
#pragma unroll
        for (int j = 0; j < 8; ++j)
            t[j] = *(const f32x4*)(bsrc + kt * 256 + j * 16);
#pragma unroll
        for (int q = 0; q < 4; ++q) {
            unsigned int o0, o1, o2, o3;
            asm("v_cvt_pk_bf16_f32 %0, %1, %2" : "=v"(o0) : "v"(t[2*q][0]),   "v"(t[2*q][1]));
            asm("v_cvt_pk_bf16_f32 %0, %1, %2" : "=v"(o1) : "v"(t[2*q][2]),   "v"(t[2*q][3]));
            asm("v_cvt_pk_bf16_f32 %0, %1, %2" : "=v"(o2) : "v"(t[2*q+1][0]), "v"(t[2*q+1][1]));
            asm("v_cvt_pk_bf16_f32 %0, %1, %2" : "=v"(o3) : "v"(t[2*q+1][2]), "v"(t[2*q+1][3]));
            *(uint4*)bdst[q] = make_uint4(o0, o1, o2, o3);
        }
        __syncthreads();                                    // drains DMA (vmcnt) + ds_writes (lgkmcnt)
#pragma unroll
        for (int kk = 0; kk < 2; ++kk) {
            bf16x8 a[4], b[4];
            const int cb = kk * 64 + cb0;
#pragma unroll
            for (int m = 0; m < 4; ++m)
                a[m] = *(const bf16x8*)((const char*)As + ((rA + m * 2048 + cb) ^ xr));
#pragma unroll
            for (int n = 0; n < 4; ++n)
                b[n] = *(const bf16x8*)((const char*)Bs + ((rB + n * 2048 + cb) ^ xr));
#pragma unroll
            for (int m = 0; m < 4; ++m)
#pragma unroll
                for (int n = 0; n < 4; ++n)
                    asm volatile("v_mfma_f32_16x16x32_bf16 %0, %1, %2, %0"
                                 : "+v"(acc[m][n]) : "v"(a[m]), "v"(b[n]));
        }
        __syncthreads();
    }
}

// ---------------- GEMM1: inter = gelu(A @ w1[e]^T + b1[e]), fp32 w1 ----------------
__global__ void __launch_bounds__(256)
gemm1_k(const unsigned short* __restrict__ ab, const float* __restrict__ w1,
        const float* __restrict__ b1, unsigned short* __restrict__ inter,
        const int* __restrict__ tile_e, const int* __restrict__ tile_r0,
        const int* __restrict__ ntiles) {
    if ((int)blockIdx.y >= *ntiles) return;
    __shared__ alignas(16) unsigned short As[128 * 64];
    __shared__ alignas(16) unsigned short Bs[128 * 64];
    const int e    = tile_e[blockIdx.y];
    const int row0 = tile_r0[blockIdx.y];
    const int f0   = blockIdx.x * 128;
    f32x4 acc[4][4];
#pragma unroll
    for (int m = 0; m < 4; ++m)
#pragma unroll
        for (int n = 0; n < 4; ++n)
#pragma unroll
            for (int j = 0; j < 4; ++j) acc[m][n][j] = 0.f;

    gemm_core<2 * H, 4 * H>((const char*)(ab + (size_t)row0 * H),
                            (const char*)(w1 + ((size_t)e * FF + f0) * H), As, Bs, acc);

    const int lane = threadIdx.x & 63;
    const int wv = threadIdx.x >> 6, wr = wv >> 1, wc = wv & 1;
    const int lr = (lane >> 4) << 2, lc = lane & 15;        // C/D: col=lane&15, row=(lane>>4)*4+reg
#pragma unroll
    for (int n = 0; n < 4; ++n) {
        const int gcol = f0 + wc * 64 + n * 16 + lc;
        const float bias = b1[e * FF + gcol];
#pragma unroll
        for (int m = 0; m < 4; ++m) {
            const int gr0 = row0 + wr * 64 + m * 16 + lr;
#pragma unroll
            for (int r = 0; r < 4; ++r) {
                float v = acc[m][n][r] + bias;
                // 0.5v(1+tanh(z)) = v - v/(e^{2z}+1), z = 0.79788456*v*(1+0.044715 v^2)
                float ex = __expf(1.5957691216057308f * v * (1.0f + 0.044715f * v * v));
                float u  = v - v / (ex + 1.0f);
                inter[(size_t)(gr0 + r) * FF + gcol] = f2bf(u);
            }
        }
    }
}

// ---------------- GEMM2: out = (inter @ w2[e]^T)*p scattered; outb = b2[e]*p fused ----------------
// r7 grid (576 1-D, panel-inner); fp32 w2 staged in-core.
__global__ void __launch_bounds__(256)
gemm2_k(const unsigned short* __restrict__ inter, const float* __restrict__ w2,
        const float* __restrict__ b2, float* __restrict__ out, float* __restrict__ outb,
        const int* __restrict__ tile_e, const int* __restrict__ tile_r0, const int* __restrict__ ntiles,
        const int* __restrict__ counts, const int* __restrict__ offs,
        const int* __restrict__ perm, const float* __restrict__ maxp) {
    const int bid = blockIdx.x;
    const int xb = bid & 7, yb = bid >> 3;
    if (yb >= *ntiles) return;
    __shared__ alignas(16) unsigned short As[128 * 64];
    __shared__ alignas(16) unsigned short Bs[128 * 64];
    const int e    = tile_e[yb];
    const int row0 = tile_r0[yb];
    const int h0   = xb * 128;
    f32x4 acc[4][4];
#pragma unroll
    for (int m = 0; m < 4; ++m)
#pragma unroll
        for (int n = 0; n < 4; ++n)
#pragma unroll
            for (int j = 0; j < 4; ++j) acc[m][n][j] = 0.f;

    gemm_core<2 * FF, 4 * FF>((const char*)(inter + (size_t)row0 * FF),
                              (const char*)(w2 + ((size_t)e * H + h0) * FF), As, Bs, acc);

    const int lane = threadIdx.x & 63;
    const int wv = threadIdx.x >> 6, wr = wv >> 1, wc = wv & 1;
    const int lr = (lane >> 4) << 2, lc = lane & 15;
    const int cnt = counts[e * 32], offe = offs[e];
#pragma unroll
    for (int m = 0; m < 4; ++m) {
#pragma unroll
        for (int r = 0; r < 4; ++r) {
            const int grow = row0 + wr * 64 + m * 16 + lr + r;
            if (grow - offe < cnt) {                         // skip padding rows
                const int t = perm[grow];
                const float p = maxp[t];
#pragma unroll
                for (int n = 0; n < 4; ++n) {
                    const int col = h0 + wc * 64 + n * 16 + lc;
                    out [(size_t)t * H + col] = acc[m][n][r] * p;
                    outb[(size_t)t * H + col] = b2[e * H + col] * p;
                }
            }
        }
    }
}

// ---------------- host launch ----------------
extern "C" void kernel_launch(void* const* d_in, const int* in_sizes, int n_in,
                              void* d_out, int out_size, void* d_ws, size_t ws_size,
                              hipStream_t stream) {
    const float* x  = (const float*)d_in[0];
    const float* rw = (const float*)d_in[1];
    const float* rb = (const float*)d_in[2];
    const float* w1 = (const float*)d_in[3];
    const float* b1 = (const float*)d_in[4];
    const float* w2 = (const float*)d_in[5];
    const float* b2 = (const float*)d_in[6];
    float* out  = (float*)d_out;                    // [8192][1024]
    float* outb = out + (size_t)NTOK * H;           // second tuple element

    // workspace layout (W1B/W2B slots retired; offsets kept stable)
    char* ws = (char*)d_ws;
    unsigned short* AB    = (unsigned short*)(ws + 134217728);     //  18874368 B (9216 x 1024 bf16)
    unsigned short* INTER = (unsigned short*)(ws + 153092096);     //  75497472 B (9216 x 4096 bf16)
    float* MAXP    = (float*)(ws + 228589568);                     //  32768 B
    int*   MAXI    = (int*)  (ws + 228622336);                     //  32768 B
    int*   PERM    = (int*)  (ws + 228655104);                     //  36864 B
    int*   COUNTS  = (int*)  (ws + 228691968);                     //  1024 B (8 x 128B)
    int*   CURSOR  = (int*)  (ws + 228692992);                     //  1024 B
    int*   OFFS    = (int*)  (ws + 228694016);                     //  64 B
    int*   TILE_E  = (int*)  (ws + 228694080);                     //  512 B
    int*   TILE_R0 = (int*)  (ws + 228694592);                     //  512 B
    int*   NTILES  = (int*)  (ws + 228695104);

    (void)hipMemsetAsync(COUNTS, 0, 2048, stream);  // counts + cursors

    router_k<<<NTOK / 4, 256, 0, stream>>>(x, rw, rb, MAXP, MAXI, COUNTS);
    scan_k<<<1, 1, 0, stream>>>(COUNTS, OFFS, TILE_E, TILE_R0, NTILES);
    gather_k<<<NTOK / 4, 256, 0, stream>>>(x, MAXI, OFFS, CURSOR, PERM, AB);
    gemm1_k<<<dim3(FF / 128, MAXT128), 256, 0, stream>>>(AB, w1, b1, INTER,
                                                         TILE_E, TILE_R0, NTILES);
    gemm2_k<<<8 * MAXT128, 256, 0, stream>>>(INTER, w2, b2, out, outb,
                                             TILE_E, TILE_R0, NTILES,
                                             COUNTS, OFFS, PERM, MAXP);
}

// Round 14
// 337.105 us; speedup vs baseline: 1.4728x; 1.4728x over previous
//
#include <hip/hip_runtime.h>
#include <math.h>

// ---------------- types ----------------
typedef float  f32x4  __attribute__((ext_vector_type(4)));
typedef short  bf16x8 __attribute__((ext_vector_type(8)));
typedef unsigned short ushort8 __attribute__((ext_vector_type(8)));

#define NTOK 8192
#define H    1024
#define FF   4096
#define NEXP 8
#define MAXT128 72   // 128-row tiles: sum ceil(c_e/128) <= 8192/128 + 8
#define NCVT  4096   // cvt blocks; chunks/matrix = NEXP*FF*H/8 = 4.19M = NCVT*256*4 exactly

// fp32 -> bf16 RNE
__device__ __forceinline__ unsigned short f2bf(float f) {
    unsigned int u = __float_as_uint(f);
    u += 0x7fffu + ((u >> 16) & 1u);
    return (unsigned short)(u >> 16);
}

__device__ __forceinline__ ushort4 cvt4(float4 v) {
    return make_ushort4(f2bf(v.x), f2bf(v.y), f2bf(v.z), f2bf(v.w));
}

__device__ __forceinline__ ushort8 pack8v(f32x4 a, f32x4 b) {
    ushort8 r;
    r[0] = f2bf(a[0]); r[1] = f2bf(a[1]); r[2] = f2bf(a[2]); r[3] = f2bf(a[3]);
    r[4] = f2bf(b[0]); r[5] = f2bf(b[1]); r[6] = f2bf(b[2]); r[7] = f2bf(b[3]);
    return r;
}

// async global->LDS, 16B/lane; LDS dest = wave-uniform base + lane*16
__device__ __forceinline__ void gload16(const void* g, void* l) {
    __builtin_amdgcn_global_load_lds((const __attribute__((address_space(1))) void*)g,
                                     (__attribute__((address_space(3))) void*)l, 16, 0, 0);
}

// ---------------- router (blocks < NTOK/4) + w1/w2 convert (remaining blocks) ----------------
// cvt uses non-temporal loads+stores (r12 measured-best variant). The conversion
// pass is fabric-bound at ~110us across r9-r12 variants; fusing it into the GEMMs
// (r13) doubled B-bytes and serialized staging -> much worse. This is the optimum.
__global__ void __launch_bounds__(256)
router_cvt_k(const float* __restrict__ x, const float* __restrict__ rw, const float* __restrict__ rb,
             float* __restrict__ maxp, int* __restrict__ maxi, int* __restrict__ counts,
             const float* __restrict__ w1, const float* __restrict__ w2,
             ushort8* __restrict__ d1, ushort8* __restrict__ d2) {
    if ((int)blockIdx.x >= NTOK / 4) {
        const int wk    = (int)blockIdx.x - NTOK / 4;
        const long tid8 = (long)wk * 256 + (int)threadIdx.x;   // 8-float chunk id
        const long CH   = (long)NCVT * 256;                    // chunk stride per j
        const f32x4* w1v = (const f32x4*)w1;
        const f32x4* w2v = (const f32x4*)w2;
#pragma unroll
        for (int j = 0; j < 4; ++j) {
            const long c = tid8 + (long)j * CH;
            f32x4 a0 = __builtin_nontemporal_load(&w1v[2 * c]);
            f32x4 a1 = __builtin_nontemporal_load(&w1v[2 * c + 1]);
            f32x4 b0 = __builtin_nontemporal_load(&w2v[2 * c]);
            f32x4 b1 = __builtin_nontemporal_load(&w2v[2 * c + 1]);
            __builtin_nontemporal_store(pack8v(a0, a1), &d1[c]);
            __builtin_nontemporal_store(pack8v(b0, b1), &d2[c]);
        }
        return;
    }
    const int lane = threadIdx.x & 63;
    const int t = blockIdx.x * 4 + (threadIdx.x >> 6);
    const float4* xr = (const float4*)(x + (size_t)t * H);
    float acc[NEXP];
#pragma unroll
    for (int e = 0; e < NEXP; ++e) acc[e] = 0.f;
#pragma unroll
    for (int c = 0; c < 4; ++c) {
        float4 xv = xr[lane + 64 * c];
#pragma unroll
        for (int e = 0; e < NEXP; ++e) {
            float4 wv = ((const float4*)(rw + e * H))[lane + 64 * c];
            acc[e] += xv.x * wv.x + xv.y * wv.y + xv.z * wv.z + xv.w * wv.w;
        }
    }
#pragma unroll
    for (int e = 0; e < NEXP; ++e) {
#pragma unroll
        for (int off = 32; off > 0; off >>= 1) acc[e] += __shfl_xor(acc[e], off);
    }
    if (lane == 0) {
        float best = -1e30f; int bi = 0;
#pragma unroll
        for (int e = 0; e < NEXP; ++e) {
            float v = acc[e] + rb[e];
            acc[e] = v;
            if (v > best) { best = v; bi = e; }   // first-max tie-break like jnp.argmax
        }
        float s = 0.f;
#pragma unroll
        for (int e = 0; e < NEXP; ++e) s += __expf(acc[e] - best);
        maxp[t] = 1.0f / s;                       // max of softmax
        maxi[t] = bi;
        atomicAdd(&counts[bi * 32], 1);           // 128B-padded: 8 independent L2 lines
    }
}

// ---------------- scan: bucket offsets (128-aligned) + 128-row tile table ----------------
__global__ void scan_k(const int* __restrict__ counts, int* __restrict__ offs,
                       int* __restrict__ tile_e, int* __restrict__ tile_r0, int* __restrict__ ntiles) {
    int off = 0, ti = 0;
    for (int e = 0; e < NEXP; ++e) {
        offs[e] = off;
        int nt = (counts[e * 32] + 127) >> 7;
        for (int j = 0; j < nt; ++j) { tile_e[ti] = e; tile_r0[ti] = off + (j << 7); ++ti; }
        off += nt << 7;
    }
    offs[NEXP] = off;
    *ntiles = ti;
}

// ---------------- gather tokens into bucketed bf16 A ----------------
__global__ void __launch_bounds__(256)
gather_k(const float* __restrict__ x, const int* __restrict__ maxi, const int* __restrict__ offs,
         int* __restrict__ cursor, int* __restrict__ perm, unsigned short* __restrict__ ab) {
    const int lane = threadIdx.x & 63;
    const int t = blockIdx.x * 4 + (threadIdx.x >> 6);
    int pos = 0;
    if (lane == 0) {
        int e = maxi[t];
        pos = offs[e] + atomicAdd(&cursor[e * 32], 1);   // padded cursors
        perm[pos] = t;
    }
    pos = __shfl(pos, 0);
    const float4* xr = (const float4*)(x + (size_t)t * H);
    ushort4* ar = (ushort4*)(ab + (size_t)pos * H);
#pragma unroll
    for (int c = 0; c < 4; ++c) {
        float4 v = xr[lane + 64 * c];
        ar[lane + 64 * c] = cvt4(v);
    }
}

// ---------------- GEMM core 128x128 (round-1 measured-best, verbatim) ----------------
// C[128x128] += A[128xK] * B[128xK]^T (both bf16 row-major, stride KB bytes).
// m97 structure: global_load_lds(16B) staging, 2 barriers / 64-elem K-step,
// 16x16x32 MFMA. LDS XOR-swizzle: linear LDS dest, inverse-swizzled GLOBAL
// source, swizzled ds_read (rule #21 pair).
template<int KB>   // row stride in bytes (= 2*K)
__device__ __forceinline__ void gemm_core(const char* Ag, const char* Bg,
                                          unsigned short* As, unsigned short* Bs,
                                          f32x4 (&acc)[4][4]) {
    const int tid  = threadIdx.x;
    const int lane = tid & 63;
    const int wv   = tid >> 6;          // 4 waves, 2x2 over tile; each wave 64x64
    const int wr   = wv >> 1, wc = wv & 1;

    int goff[4];
#pragma unroll
    for (int c = 0; c < 4; ++c) {
        int op = c * 4096 + wv * 1024 + lane * 16;          // physical LDS byte this lane fills
        int ol = op ^ (((op >> 7) & 7) << 4);               // logical offset (swz is an involution)
        goff[c] = (ol >> 7) * KB + (ol & 127);              // row*stride + col bytes
    }
    const int rA  = (wr * 64 + (lane & 15)) * 128;
    const int rB  = (wc * 64 + (lane & 15)) * 128;
    const int xr  = (lane & 7) << 4;                        // (row&7)<<4 swizzle on read
    const int cb0 = (lane >> 4) << 4;

#pragma unroll 1
    for (int kt = 0; kt < KB / 128; ++kt) {
        const int kb = kt * 128;
#pragma unroll
        for (int c = 0; c < 4; ++c)
            gload16(Ag + goff[c] + kb, (char*)As + c * 4096 + wv * 1024);
#pragma unroll
        for (int c = 0; c < 4; ++c)
            gload16(Bg + goff[c] + kb, (char*)Bs + c * 4096 + wv * 1024);
        __syncthreads();                                    // drains vmcnt(0) for the LDS DMA
#pragma unroll
        for (int kk = 0; kk < 2; ++kk) {
            bf16x8 a[4], b[4];
            const int cb = kk * 64 + cb0;
#pragma unroll
            for (int m = 0; m < 4; ++m)
                a[m] = *(const bf16x8*)((const char*)As + ((rA + m * 2048 + cb) ^ xr));
#pragma unroll
            for (int n = 0; n < 4; ++n)
                b[n] = *(const bf16x8*)((const char*)Bs + ((rB + n * 2048 + cb) ^ xr));
#pragma unroll
            for (int m = 0; m < 4; ++m)
#pragma unroll
                for (int n = 0; n < 4; ++n)
                    asm volatile("v_mfma_f32_16x16x32_bf16 %0, %1, %2, %0"
                                 : "+v"(acc[m][n]) : "v"(a[m]), "v"(b[n]));
        }
        __syncthreads();
    }
}

// ---------------- GEMM1: inter = gelu(A @ w1[e]^T + b1[e]) (r5 verbatim) ----------------
__global__ void __launch_bounds__(256)
gemm1_k(const unsigned short* __restrict__ ab, const unsigned short* __restrict__ w1b,
        const float* __restrict__ b1, unsigned short* __restrict__ inter,
        const int* __restrict__ tile_e, const int* __restrict__ tile_r0,
        const int* __restrict__ ntiles) {
    if ((int)blockIdx.y >= *ntiles) return;
    __shared__ alignas(16) unsigned short As[128 * 64];
    __shared__ alignas(16) unsigned short Bs[128 * 64];
    const int e    = tile_e[blockIdx.y];
    const int row0 = tile_r0[blockIdx.y];
    const int f0   = blockIdx.x * 128;
    f32x4 acc[4][4];
#pragma unroll
    for (int m = 0; m < 4; ++m)
#pragma unroll
        for (int n = 0; n < 4; ++n)
#pragma unroll
            for (int j = 0; j < 4; ++j) acc[m][n][j] = 0.f;

    gemm_core<2 * H>((const char*)(ab + (size_t)row0 * H),
                     (const char*)(w1b + ((size_t)e * FF + f0) * H), As, Bs, acc);

    const int lane = threadIdx.x & 63;
    const int wv = threadIdx.x >> 6, wr = wv >> 1, wc = wv & 1;
    const int lr = (lane >> 4) << 2, lc = lane & 15;        // C/D: col=lane&15, row=(lane>>4)*4+reg
#pragma unroll
    for (int n = 0; n < 4; ++n) {
        const int gcol = f0 + wc * 64 + n * 16 + lc;
        const float bias = b1[e * FF + gcol];
#pragma unroll
        for (int m = 0; m < 4; ++m) {
            const int gr0 = row0 + wr * 64 + m * 16 + lr;
#pragma unroll
            for (int r = 0; r < 4; ++r) {
                float v = acc[m][n][r] + bias;
                // 0.5v(1+tanh(z)) = v - v/(e^{2z}+1), z = 0.79788456*v*(1+0.044715 v^2)
                float ex = __expf(1.5957691216057308f * v * (1.0f + 0.044715f * v * v));
                float u  = v - v / (ex + 1.0f);
                inter[(size_t)(gr0 + r) * FF + gcol] = f2bf(u);
            }
        }
    }
}

// ---------------- GEMM2: out = (inter @ w2[e]^T)*p scattered; outb = b2[e]*p fused ----------------
// r7 measured-best: BN=128, 1-D grid 576, panel-inner ordering, fused outb.
__global__ void __launch_bounds__(256)
gemm2_k(const unsigned short* __restrict__ inter, const unsigned short* __restrict__ w2b,
        const float* __restrict__ b2, float* __restrict__ out, float* __restrict__ outb,
        const int* __restrict__ tile_e, const int* __restrict__ tile_r0, const int* __restrict__ ntiles,
        const int* __restrict__ counts, const int* __restrict__ offs,
        const int* __restrict__ perm, const float* __restrict__ maxp) {
    const int bid = blockIdx.x;
    const int xb = bid & 7, yb = bid >> 3;
    if (yb >= *ntiles) return;
    __shared__ alignas(16) unsigned short As[128 * 64];
    __shared__ alignas(16) unsigned short Bs[128 * 64];
    const int e    = tile_e[yb];
    const int row0 = tile_r0[yb];
    const int h0   = xb * 128;
    f32x4 acc[4][4];
#pragma unroll
    for (int m = 0; m < 4; ++m)
#pragma unroll
        for (int n = 0; n < 4; ++n)
#pragma unroll
            for (int j = 0; j < 4; ++j) acc[m][n][j] = 0.f;

    gemm_core<2 * FF>((const char*)(inter + (size_t)row0 * FF),
                      (const char*)(w2b + ((size_t)e * H + h0) * FF), As, Bs, acc);

    const int lane = threadIdx.x & 63;
    const int wv = threadIdx.x >> 6, wr = wv >> 1, wc = wv & 1;
    const int lr = (lane >> 4) << 2, lc = lane & 15;
    const int cnt = counts[e * 32], offe = offs[e];
#pragma unroll
    for (int m = 0; m < 4; ++m) {
#pragma unroll
        for (int r = 0; r < 4; ++r) {
            const int grow = row0 + wr * 64 + m * 16 + lr + r;
            if (grow - offe < cnt) {                         // skip padding rows
                const int t = perm[grow];
                const float p = maxp[t];
#pragma unroll
                for (int n = 0; n < 4; ++n) {
                    const int col = h0 + wc * 64 + n * 16 + lc;
                    out [(size_t)t * H + col] = acc[m][n][r] * p;
                    outb[(size_t)t * H + col] = b2[e * H + col] * p;
                }
            }
        }
    }
}

// ---------------- host launch ----------------
extern "C" void kernel_launch(void* const* d_in, const int* in_sizes, int n_in,
                              void* d_out, int out_size, void* d_ws, size_t ws_size,
                              hipStream_t stream) {
    const float* x  = (const float*)d_in[0];
    const float* rw = (const float*)d_in[1];
    const float* rb = (const float*)d_in[2];
    const float* w1 = (const float*)d_in[3];
    const float* b1 = (const float*)d_in[4];
    const float* w2 = (const float*)d_in[5];
    const float* b2 = (const float*)d_in[6];
    float* out  = (float*)d_out;                    // [8192][1024]
    float* outb = out + (size_t)NTOK * H;           // second tuple element

    // workspace layout (~219 MB)
    char* ws = (char*)d_ws;
    unsigned short* W1B   = (unsigned short*)(ws);                 //  67108864 B
    unsigned short* W2B   = (unsigned short*)(ws + 67108864);      //  67108864 B
    unsigned short* AB    = (unsigned short*)(ws + 134217728);     //  18874368 B (9216 x 1024 bf16)
    unsigned short* INTER = (unsigned short*)(ws + 153092096);     //  75497472 B (9216 x 4096 bf16)
    float* MAXP    = (float*)(ws + 228589568);                     //  32768 B
    int*   MAXI    = (int*)  (ws + 228622336);                     //  32768 B
    int*   PERM    = (int*)  (ws + 228655104);                     //  36864 B
    int*   COUNTS  = (int*)  (ws + 228691968);                     //  1024 B (8 x 128B)
    int*   CURSOR  = (int*)  (ws + 228692992);                     //  1024 B
    int*   OFFS    = (int*)  (ws + 228694016);                     //  64 B
    int*   TILE_E  = (int*)  (ws + 228694080);                     //  512 B
    int*   TILE_R0 = (int*)  (ws + 228694592);                     //  512 B
    int*   NTILES  = (int*)  (ws + 228695104);

    (void)hipMemsetAsync(COUNTS, 0, 2048, stream);  // counts + cursors

    router_cvt_k<<<NTOK / 4 + NCVT, 256, 0, stream>>>(x, rw, rb, MAXP, MAXI, COUNTS,
                                                      w1, w2,
                                                      (ushort8*)W1B, (ushort8*)W2B);
    scan_k<<<1, 1, 0, stream>>>(COUNTS, OFFS, TILE_E, TILE_R0, NTILES);
    gather_k<<<NTOK / 4, 256, 0, stream>>>(x, MAXI, OFFS, CURSOR, PERM, AB);
    gemm1_k<<<dim3(FF / 128, MAXT128), 256, 0, stream>>>(AB, W1B, b1, INTER,
                                                         TILE_E, TILE_R0, NTILES);
    gemm2_k<<<8 * MAXT128, 256, 0, stream>>>(INTER, W2B, b2, out, outb,
                                             TILE_E, TILE_R0, NTILES,
                                             COUNTS, OFFS, PERM, MAXP);
}